// Round 9
// baseline (99.154 us; speedup 1.0000x reference)
//
#include <hip/hip_runtime.h>

// B=128, K=256, M=8, D=128 ; rows = B*K = 32768 flattened (b,k)
// r8: compact positive rows (label==1), ~halves real work.
// r9: concept-split 2x + rf=2 A-reuse -> halves chunk-wave instance count
//     (fixed per-instance cost: 8 ds_read_b128 + staging + 2 barriers).
#define LT      20.0f
#define LN2     0.69314718055994531f
#define C2EXP   28.853900817779268f   // LT/ln2 : e^(LT*x) = 2^(C2EXP*x)
#define CHUNKS_H 8                    // chunks per concept-half (8 x 128 cols)
#define NBLK    1024                  // worst case: 512 row-groups x 2 halves

typedef _Float16 half8 __attribute__((ext_vector_type(8)));
typedef float    f32x4 __attribute__((ext_vector_type(4)));

#if __has_builtin(__builtin_amdgcn_exp2f)
#define EXP2F(x) __builtin_amdgcn_exp2f(x)
#else
#define EXP2F(x) __expf(0.69314718055994531f * (x))
#endif

__device__ __forceinline__ float swz16(float x) {
    // xor lane^16 within 32-lane halves (BitMode: xor=16, and=0x1F)
    return __int_as_float(__builtin_amdgcn_ds_swizzle(__float_as_int(x), 0x401F));
}

// async global->LDS, 16B per lane; lds base must be wave-uniform
#define GLD16(gp, lp) __builtin_amdgcn_global_load_lds( \
    (const __attribute__((address_space(1))) void*)(gp), \
    (__attribute__((address_space(3))) void*)(lp), 16, 0, 0)

// ---- prep: f32 P -> f16 scaled by C2EXP, packed in fragment lane order.
// Coalesced reads (16 threads per contiguous 512B P row), scattered 16B
// writes into L2-resident Pw. slot = ch*2048 + colq*512 + cfrag*64 + lane,
// lane=(q<<4)|n, cfrag=(h<<2)|c, col=colq*32+(n>>2)*8+(n&3)+4h, d=c*32+q*8
__global__ __launch_bounds__(256)
void mpcl_prep(const float* __restrict__ P, _Float16* __restrict__ Pw)
{
    int t    = blockIdx.x * 256 + threadIdx.x;   // 0..32767
    int gcol = t >> 4;                           // 0..2047 (concept*8+proto)
    int dblk = t & 15;                           // d/8
    const float* src = P + ((size_t)gcol << 7) + dblk * 8;
    float4 a = *(const float4*)src;
    float4 b = *(const float4*)(src + 4);

    int ch   = gcol >> 7, col  = gcol & 127;
    int colq = col >> 5,  col5 = col & 31;
    int g = col5 >> 3, p = col5 & 7;             // proto-group, proto
    int n = (g << 2) | (p & 3), h = p >> 2;
    int c = dblk >> 2, q = dblk & 3;
    int lane  = (q << 4) | n;
    int cfrag = (h << 2) | c;
    int slot  = ch * 2048 + colq * 512 + cfrag * 64 + lane;

    half8 hv;   // pre-scaled: MFMA emits y = C2EXP * sim directly
    hv[0] = (_Float16)(C2EXP * a.x); hv[1] = (_Float16)(C2EXP * a.y);
    hv[2] = (_Float16)(C2EXP * a.z); hv[3] = (_Float16)(C2EXP * a.w);
    hv[4] = (_Float16)(C2EXP * b.x); hv[5] = (_Float16)(C2EXP * b.y);
    hv[6] = (_Float16)(C2EXP * b.z); hv[7] = (_Float16)(C2EXP * b.w);
    *(half8*)(Pw + (size_t)slot * 8) = hv;
}

// ---- compact: ordered list of rows with label==1 (deterministic).
__global__ __launch_bounds__(1024)
void mpcl_compact(const int* __restrict__ labels, int* __restrict__ ridx,
                  int* __restrict__ npos)
{
    __shared__ int wcnt[512];
    __shared__ int wsum[8];
    __shared__ int sbase[512];
    __shared__ int tot;
    const int tid = threadIdx.x, lane = tid & 63, w = tid >> 6;   // w 0..15

    int lab[32];
#pragma unroll
    for (int i = 0; i < 32; ++i) lab[i] = labels[i * 1024 + tid];
#pragma unroll
    for (int i = 0; i < 32; ++i) {
        unsigned long long m = __ballot(lab[i] == 1);
        if (lane == 0) wcnt[i * 16 + w] = __popcll(m);
    }
    __syncthreads();

    int v = 0, orig = 0;
    if (tid < 512) { v = wcnt[tid]; orig = v; }
#pragma unroll
    for (int off = 1; off < 64; off <<= 1) {             // intra-wave scan
        int t = __shfl_up(v, off);
        if (lane >= off) v += t;
    }
    if (lane == 63 && w < 8) wsum[w] = v;
    __syncthreads();
    if (tid == 0) {
        int acc = 0;
#pragma unroll
        for (int i = 0; i < 8; ++i) { int t = wsum[i]; wsum[i] = acc; acc += t; }
        tot = acc; npos[0] = acc;
    }
    __syncthreads();
    if (tid < 512) sbase[tid] = v - orig + wsum[w];      // exclusive base
    __syncthreads();

#pragma unroll
    for (int i = 0; i < 32; ++i) {                       // ordered scatter
        unsigned long long m = __ballot(lab[i] == 1);
        int pos = sbase[i * 16 + w] + __popcll(m & ((1ull << lane) - 1));
        if (lab[i] == 1) ridx[pos] = i * 1024 + tid;
    }
    for (int j = tot + tid; j < 32768; j += 1024) ridx[j] = 0;   // pad
}

// Grid: 1024 blocks x 512 thr (8 waves). Block = (row-group g, half h):
// 64 COMPACTED rows x concepts [h*128, h*128+128) = 8 chunks.
// wave w: colq=w&3, rg=w>>2 (32 rows, 2 rf). Per chunk-wave: 8 ds_read_b128
// A-frags REUSED across 2 rf (16 MFMA), 2 epilogues -> half the instances
// of r8 at the same total MFMA/epi work. Active blocks = 2*ceil(np/64)
// (~512 @ np~16k) = 2/CU, dbuf 64KB LDS, counted vmcnt (never 0 mid-loop).
// Per-row denominators are HALF-sums -> finisher adds the two halves and
// takes the log (exact: denom is a sum over concepts).
__global__ __attribute__((amdgpu_flat_work_group_size(512, 512),
                          amdgpu_waves_per_eu(4, 4)))
void mpcl_main(const float* __restrict__ V,        // (32768, 128) f32
               const _Float16* __restrict__ Pw,    // packed P (prep)
               const int* __restrict__ ridx,       // compacted rows
               const int* __restrict__ npos,
               float* __restrict__ dnw)            // [0]:dn_h0 [32768]:dn_h1 [65536]:simY
{
    __shared__ __align__(16) _Float16 Pst[2][2048 * 8];   // 2 x 32 KB
    __shared__ float sh_denom[64];
    __shared__ float sh_simpos[64];

    const int np = *npos;
    const int h  = blockIdx.x & 1;                // concept half
    const int rowbase = (blockIdx.x >> 1) * 64;   // compacted row base
    if (rowbase >= np) return;                    // uniform early exit

    const int tid  = threadIdx.x;
    const int lane = tid & 63;
    const int w    = tid >> 6;        // 0..7
    const int colq = w & 3;
    const int rg   = w >> 2;          // 0..1 -> 32-row group
    const int n    = lane & 15;
    const int q    = lane >> 4;

    if (tid < 64) { sh_denom[tid] = 0.0f; sh_simpos[tid] = 0.0f; }

    // wave w stages half8 slots [w*256, +256) of each chunk: 4 GLD16
    const _Float16* gbase = Pw + (size_t)h * (CHUNKS_H * 16384)
                               + (size_t)(w * 256 + lane) * 8;

#define STAGE(CH, B) do {                                       \
    const _Float16* g_ = gbase + (size_t)(CH) * 16384;          \
    _Float16* l_ = &Pst[B][(w * 256) * 8];                      \
    GLD16(g_,        l_);                                       \
    GLD16(g_ +  512, l_ +  512);                                \
    GLD16(g_ + 1024, l_ + 1024);                                \
    GLD16(g_ + 1536, l_ + 1536);                                \
} while (0)

    // ---- V fragments (B operand): 2 rf x 16 gathered rows, reg-resident ----
    int myrow[2];
    half8 vh[2][4];
#pragma unroll
    for (int rf = 0; rf < 2; ++rf) {
        int pos = rowbase + rg * 32 + rf * 16 + n;
        myrow[rf] = ridx[pos < np ? pos : np - 1];   // clamped gather
        const float* vr = V + ((size_t)myrow[rf] << 7) + q * 8;
#pragma unroll
        for (int c = 0; c < 4; ++c) {
            float4 x0 = *(const float4*)(vr + c * 32);
            float4 x1 = *(const float4*)(vr + c * 32 + 4);
            vh[rf][c][0] = (_Float16)x0.x; vh[rf][c][1] = (_Float16)x0.y;
            vh[rf][c][2] = (_Float16)x0.z; vh[rf][c][3] = (_Float16)x0.w;
            vh[rf][c][4] = (_Float16)x1.x; vh[rf][c][5] = (_Float16)x1.y;
            vh[rf][c][6] = (_Float16)x1.z; vh[rf][c][7] = (_Float16)x1.w;
        }
    }
    __syncthreads();   // sh_* init visible before any epilogue writes

    STAGE(0, 0);       // chunks 0+1 in flight (8 outstanding per wave)
    STAGE(1, 1);

    const int rowk0 = myrow[0] & 255;             // rows' own concepts
    const int rowk1 = myrow[1] & 255;
    const int aoff  = (colq * 512 + lane) * 8;    // half index of a1(c=0)

    float dn0 = 0.f, dn1 = 0.f;
    int cA = h * 128 + colq * 4 + q;              // this lane's concept

#pragma unroll 1
    for (int ch = 0; ch < CHUNKS_H; ++ch) {
        // steady state: this chunk's 4 loads done, next chunk's 4 in flight
        if (ch < CHUNKS_H - 1) asm volatile("s_waitcnt vmcnt(4)" ::: "memory");
        else                   asm volatile("s_waitcnt vmcnt(0)" ::: "memory");
        __builtin_amdgcn_s_barrier();   // all waves' chunk-ch DMA visible

        const _Float16* base = &Pst[ch & 1][0];

        f32x4 acc1[2] = {{0.f,0.f,0.f,0.f},{0.f,0.f,0.f,0.f}};
        f32x4 acc2[2] = {{0.f,0.f,0.f,0.f},{0.f,0.f,0.f,0.f}};
#pragma unroll
        for (int c = 0; c < 4; ++c) {
            half8 a1 = *(const half8*)&base[aoff + c * 512];          // frag c
            half8 a2 = *(const half8*)&base[aoff + c * 512 + 2048];   // frag 4+c
            acc1[0] = __builtin_amdgcn_mfma_f32_16x16x32_f16(a1, vh[0][c], acc1[0], 0, 0, 0);
            acc1[1] = __builtin_amdgcn_mfma_f32_16x16x32_f16(a1, vh[1][c], acc1[1], 0, 0, 0);
            acc2[0] = __builtin_amdgcn_mfma_f32_16x16x32_f16(a2, vh[0][c], acc2[0], 0, 0, 0);
            acc2[1] = __builtin_amdgcn_mfma_f32_16x16x32_f16(a2, vh[1][c], acc2[1], 0, 0, 0);
        }

        asm volatile("s_waitcnt lgkmcnt(0)" ::: "memory");  // ds_reads retired
        __builtin_amdgcn_s_barrier();   // all waves done reading Pst[ch&1]
        if (ch + 2 < CHUNKS_H) STAGE(ch + 2, ch & 1);  // DMA hides under epi

        // ---- epilogue x2: y = C2EXP*sim; softmax-over-8 in-lane ----
#pragma unroll
        for (int rf = 0; rf < 2; ++rf) {
            float x0 = acc1[rf][0], x1 = acc1[rf][1], x2 = acc1[rf][2], x3 = acc1[rf][3];
            float x4 = acc2[rf][0], x5 = acc2[rf][1], x6 = acc2[rf][2], x7 = acc2[rf][3];
            float e0 = EXP2F(x0), e1 = EXP2F(x1), e2 = EXP2F(x2), e3 = EXP2F(x3);
            float e4 = EXP2F(x4), e5 = EXP2F(x5), e6 = EXP2F(x6), e7 = EXP2F(x7);
            float es = ((e0 + e1) + (e2 + e3)) + ((e4 + e5) + (e6 + e7));
            float ss = fmaf(e0, x0, fmaf(e1, x1, fmaf(e2, x2, e3 * x3)))
                     + fmaf(e4, x4, fmaf(e5, x5, fmaf(e6, x6, e7 * x7)));
            float simY = __fdividef(ss, es);          // = C2EXP * sim_c
            if (rf) dn1 += EXP2F(simY); else dn0 += EXP2F(simY);
            if (cA == (rf ? rowk1 : rowk0))
                sh_simpos[rg * 32 + rf * 16 + n] = simY;   // unique writer
        }
        cA += 16;
    }

    // ---- fold half-denominators over the 4 q-groups ----
#pragma unroll
    for (int rf = 0; rf < 2; ++rf) {
        float t = rf ? dn1 : dn0;
        t += swz16(t);                 // q 0<->1, 2<->3
        t += __shfl_xor(t, 32);        // q 0<->2
        if (lane < 16)
            atomicAdd(&sh_denom[rg * 32 + rf * 16 + n], t);
    }
    __syncthreads();

    // ---- plain per-row partial stores; finisher combines halves ----
    if (w == 0) {                     // lanes 0..63 <-> block's 64 rows
        int pos = rowbase + lane;
        int mr  = ridx[pos < np ? pos : np - 1];
        dnw[h * 32768 + pos] = sh_denom[lane];
        if (((mr & 255) >> 7) == h)                    // positive concept here?
            dnw[65536 + pos] = sh_simpos[lane];        // simY_pos
    }
}

// 1 block x 1024 thr: per-row log(dn0+dn1+eps) - ln2*simY - 1, mean over np.
// Visibility of mpcl_main's stores guaranteed by stream ordering.
__global__ __launch_bounds__(1024)
void mpcl_finish(const float* __restrict__ dnw, const int* __restrict__ npos,
                 float* __restrict__ out)
{
    __shared__ float sh[16];
    const int tid  = threadIdx.x;
    const int lane = tid & 63;
    const int w    = tid >> 6;
    const int np   = *npos;

    float s = 0.f;
    for (int i = tid; i < np; i += 1024) {
        float dn = dnw[i] + dnw[32768 + i];
        s += logf(dn + 1e-8f) - LN2 * dnw[65536 + i] - 1.0f;
    }
#pragma unroll
    for (int off = 32; off >= 1; off >>= 1) s += __shfl_down(s, off);
    if (lane == 0) sh[w] = s;
    __syncthreads();
    if (tid == 0) {
        float ts = 0.f;
#pragma unroll
        for (int i = 0; i < 16; ++i) ts += sh[i];
        out[0] = (np > 0) ? (ts / (float)np) : 0.0f;
    }
}

extern "C" void kernel_launch(void* const* d_in, const int* in_sizes, int n_in,
                              void* d_out, int out_size, void* d_ws, size_t ws_size,
                              hipStream_t stream)
{
    const float* V      = (const float*)d_in[0];
    const int*   labels = (const int*)d_in[1];
    const float* P      = (const float*)d_in[2];
    float* out = (float*)d_out;

    int*      npos = (int*)d_ws;                        // [0]
    float*    dnw  = (float*)((char*)d_ws + 4096);      // 3 x 32768 floats
    int*      ridx = (int*)((char*)d_ws + 397312);      // 128 KB
    _Float16* Pw   = (_Float16*)((char*)d_ws + 528384); // 512 KB packed P

    mpcl_prep<<<128, 256, 0, stream>>>(P, Pw);
    mpcl_compact<<<1, 1024, 0, stream>>>(labels, ridx, npos);
    mpcl_main<<<NBLK, 512, 0, stream>>>(V, Pw, ridx, npos, dnw);
    mpcl_finish<<<1, 1024, 0, stream>>>(dnw, npos, out);
}

// Round 10
// 93.971 us; speedup vs baseline: 1.0552x; 1.0552x over previous
//
#include <hip/hip_runtime.h>

// B=128, K=256, M=8, D=128 ; rows = B*K = 32768 flattened (b,k)
// r8: compact positive rows (label==1) -> ~half the work.      [93.7us best]
// r10: 32x32x16 MFMA (2x FLOP per 16B A-read -> ds_read/work halves) +
//      per-wave PRIVATE LDS stripes -> ZERO barriers in K-loop + merged
//      prep+compact dispatch.
#define LT      20.0f
#define LN2     0.69314718055994531f
#define C2EXP   28.853900817779268f   // LT/ln2 : e^(LT*x) = 2^(C2EXP*x)
#define CHUNKS  16                    // 16 chunks x 128 prototype-cols
#define NBLK    1024                  // worst case ceil(32768/32)

typedef _Float16 half8  __attribute__((ext_vector_type(8)));
typedef float    f32x16 __attribute__((ext_vector_type(16)));

#if __has_builtin(__builtin_amdgcn_exp2f)
#define EXP2F(x) __builtin_amdgcn_exp2f(x)
#else
#define EXP2F(x) __expf(0.69314718055994531f * (x))
#endif

// async global->LDS, 16B per lane; lds base must be wave-uniform
#define GLD16(gp, lp) __builtin_amdgcn_global_load_lds( \
    (const __attribute__((address_space(1))) void*)(gp), \
    (__attribute__((address_space(3))) void*)(lp), 16, 0, 0)

// ---------------- layout derivation (32x32x16_f16) ----------------
// C/D: col n = lane&31 (V-row), row m = (reg&3) + 8*(reg>>2) + 4*(lane>>5)
//   [HW-verified mapping, dtype-independent]
// A: lane holds A-row (lane&31), k = (lane>>5)*8 + j  (K=16, 8 halves)
// B: lane holds B-col (lane&31), k = (lane>>5)*8 + j
// A-row permutation sigma: place concept c_loc, proto p at A-row
//   a = (p&3) | ((c_loc&1)<<2) | ((c_loc>>1)<<3) | ((p>>2)<<4)
// => lane hi=lane>>5 gets acc regs covering COMPLETE concepts:
//   concept c_loc=hi   : regs {0..3}=p0..3, {8..11}=p4..7
//   concept c_loc=hi+2 : regs {4..7}=p0..3, {12..15}=p4..7
// Pw slot id = ch*2048 + (g*8 + s)*64 + lane  (half8 each), where
//   g = 4-concept group in chunk (0..3), s = K-slice d=[16s,16s+16),
//   half j = C2EXP * P[ch*128 + g*32 + c_loc*8 + p][s*16 + hi*8 + j]
// Main: wave w(=g) stages slots [w*512,+512) linearly (8 GLD16) and reads
// ONLY that stripe -> per-wave private pipeline, no barriers needed.

// ---- merged prep (blocks 0..31) + compact (block 32) ----
__global__ __launch_bounds__(1024)
void mpcl_prep_compact(const float* __restrict__ P,
                       const int*   __restrict__ labels,
                       _Float16* __restrict__ Pw,
                       int* __restrict__ ridx, int* __restrict__ npos)
{
    __shared__ int wcnt[512];
    __shared__ int wsum[8];
    __shared__ int sbase[512];
    __shared__ int tot;

    if (blockIdx.x < 32) {
        // ---- prep: coalesced reads (16 thr per contiguous 512B P row) ----
        int t    = blockIdx.x * 1024 + threadIdx.x;   // 0..32767
        int gcol = t >> 4;                            // concept*8+proto col
        int dblk = t & 15;                            // d/8
        const float* src = P + ((size_t)gcol << 7) + dblk * 8;
        float4 x0 = *(const float4*)src;
        float4 x1 = *(const float4*)(src + 4);

        int ch = gcol >> 7, col = gcol & 127;
        int g  = col >> 5,  col5 = col & 31;
        int cl = col5 >> 3, p = col5 & 7;             // concept-local, proto
        int a  = (p & 3) | ((cl & 1) << 2) | ((cl >> 1) << 3) | ((p >> 2) << 4);
        int hi = dblk & 1, s = dblk >> 1;
        int l  = (hi << 5) | a;
        int slot = ch * 2048 + (g * 8 + s) * 64 + l;

        half8 hv;   // pre-scaled: MFMA emits y = C2EXP * sim directly
        hv[0] = (_Float16)(C2EXP * x0.x); hv[1] = (_Float16)(C2EXP * x0.y);
        hv[2] = (_Float16)(C2EXP * x0.z); hv[3] = (_Float16)(C2EXP * x0.w);
        hv[4] = (_Float16)(C2EXP * x1.x); hv[5] = (_Float16)(C2EXP * x1.y);
        hv[6] = (_Float16)(C2EXP * x1.z); hv[7] = (_Float16)(C2EXP * x1.w);
        *(half8*)(Pw + (size_t)slot * 8) = hv;
    } else {
        // ---- compact (r8-verbatim): ordered list of label==1 rows ----
        const int tid = threadIdx.x, lane = tid & 63, w = tid >> 6;
        int lab[32];
#pragma unroll
        for (int i = 0; i < 32; ++i) lab[i] = labels[i * 1024 + tid];
#pragma unroll
        for (int i = 0; i < 32; ++i) {
            unsigned long long m = __ballot(lab[i] == 1);
            if (lane == 0) wcnt[i * 16 + w] = __popcll(m);
        }
        __syncthreads();

        int v = 0, orig = 0;
        if (tid < 512) { v = wcnt[tid]; orig = v; }
#pragma unroll
        for (int off = 1; off < 64; off <<= 1) {      // intra-wave scan
            int t2 = __shfl_up(v, off);
            if (lane >= off) v += t2;
        }
        if (lane == 63 && w < 8) wsum[w] = v;
        __syncthreads();
        if (tid == 0) {
            int acc = 0;
#pragma unroll
            for (int i = 0; i < 8; ++i) { int t2 = wsum[i]; wsum[i] = acc; acc += t2; }
            tot = acc; npos[0] = acc;
        }
        __syncthreads();
        if (tid < 512) sbase[tid] = v - orig + wsum[w];
        __syncthreads();

#pragma unroll
        for (int i = 0; i < 32; ++i) {                // ordered scatter
            unsigned long long m = __ballot(lab[i] == 1);
            int pos = sbase[i * 16 + w] + __popcll(m & ((1ull << lane) - 1));
            if (lab[i] == 1) ridx[pos] = i * 1024 + tid;
        }
        for (int j = tot + tid; j < 32768; j += 1024) ridx[j] = 0;   // pad
    }
}

// Grid: 1024 blocks x 256 thr (4 waves); ~512 active (2/CU), rest exit.
// Block owns 32 COMPACTED rows x all 2048 cols. Wave w = concept-group g.
// Per chunk per wave: 8 ds_read_b128 -> 8 mfma_32x32x16 (2 chains of 4)
// -> 2 in-lane softmax-8s. Wave stages/reads its PRIVATE 8KB LDS stripe:
// NO barriers in the K-loop; per-wave counted vmcnt(8) (never 0 mid-loop),
// lgkmcnt(0) before restaging the buffer it just read. Waves free-run.
__global__ __attribute__((amdgpu_flat_work_group_size(256, 256),
                          amdgpu_waves_per_eu(4, 4)))
void mpcl_main(const float* __restrict__ V,        // (32768, 128) f32
               const _Float16* __restrict__ Pw,    // packed P (prep)
               const int* __restrict__ ridx,       // compacted rows
               const int* __restrict__ npos,
               float* __restrict__ part)           // (NBLK, 2) partials
{
    __shared__ __align__(16) _Float16 Pst[2][16384];   // 2 x 32 KB
    __shared__ float sh_denom[32];
    __shared__ float sh_simpos[32];

    const int np = *npos;
    const int rowbase = blockIdx.x * 32;
    if (rowbase >= np) return;                    // uniform early exit

    const int tid = threadIdx.x;
    const int l   = tid & 63;
    const int w   = tid >> 6;       // 0..3 = concept-group g
    const int a   = l & 31;         // V-row slot AND A-row index
    const int hi  = l >> 5;

    if (tid < 32) sh_denom[tid] = 0.0f;

    const int pos   = rowbase + a;
    const int myrow = ridx[pos < np ? pos : np - 1];   // clamped gather
    const int rowk  = myrow & 255;                     // row's own concept

    // ---- V fragments: lane holds row (l&31), d = s*16 + hi*8 + j ----
    half8 vh[8];
    {
        const float* vr = V + ((size_t)myrow << 7) + hi * 8;
#pragma unroll
        for (int s = 0; s < 8; ++s) {
            float4 x0 = *(const float4*)(vr + s * 16);
            float4 x1 = *(const float4*)(vr + s * 16 + 4);
            vh[s][0] = (_Float16)x0.x; vh[s][1] = (_Float16)x0.y;
            vh[s][2] = (_Float16)x0.z; vh[s][3] = (_Float16)x0.w;
            vh[s][4] = (_Float16)x1.x; vh[s][5] = (_Float16)x1.y;
            vh[s][6] = (_Float16)x1.z; vh[s][7] = (_Float16)x1.w;
        }
    }
    __syncthreads();   // sh_denom init visible (only pre-loop barrier)

    // wave w stages its private stripe: slots [w*512, +512) of each chunk
    const _Float16* gbase = Pw + (size_t)(w * 512 + l) * 8;

#define STAGE(CH, B) do {                                       \
    const _Float16* g_ = gbase + (size_t)(CH) * 16384;          \
    _Float16* l_ = &Pst[B][w * 4096];                           \
    GLD16(g_,        l_);        GLD16(g_ +  512, l_ +  512);   \
    GLD16(g_ + 1024, l_ + 1024); GLD16(g_ + 1536, l_ + 1536);   \
    GLD16(g_ + 2048, l_ + 2048); GLD16(g_ + 2560, l_ + 2560);   \
    GLD16(g_ + 3072, l_ + 3072); GLD16(g_ + 3584, l_ + 3584);   \
} while (0)

    STAGE(0, 0);       // chunks 0+1 in flight (16 outstanding per wave)
    STAGE(1, 1);

    float dn = 0.f;

#define SOFT8(y0,y1,y2,y3,y4,y5,y6,y7, CONCEPT) do {                        \
    float e0=EXP2F(y0), e1=EXP2F(y1), e2=EXP2F(y2), e3=EXP2F(y3);           \
    float e4=EXP2F(y4), e5=EXP2F(y5), e6=EXP2F(y6), e7=EXP2F(y7);           \
    float es = ((e0+e1)+(e2+e3)) + ((e4+e5)+(e6+e7));                       \
    float ss = fmaf(e0,y0, fmaf(e1,y1, fmaf(e2,y2, e3*y3)))                 \
             + fmaf(e4,y4, fmaf(e5,y5, fmaf(e6,y6, e7*y7)));                \
    float simY = __fdividef(ss, es);            /* = C2EXP * sim_c */       \
    dn += EXP2F(simY);                                                      \
    if ((CONCEPT) == rowk) sh_simpos[a] = simY; /* unique lane per concept */\
} while (0)

#pragma unroll 1
    for (int ch = 0; ch < CHUNKS; ++ch) {
        // per-wave wait: this chunk's 8 loads done, next chunk's 8 in flight
        if (ch < CHUNKS - 1) asm volatile("s_waitcnt vmcnt(8)" ::: "memory");
        else                 asm volatile("s_waitcnt vmcnt(0)" ::: "memory");

        const _Float16* bs = &Pst[ch & 1][w * 4096];
        f32x16 acA = {0.f,0.f,0.f,0.f,0.f,0.f,0.f,0.f,0.f,0.f,0.f,0.f,0.f,0.f,0.f,0.f};
        f32x16 acB = {0.f,0.f,0.f,0.f,0.f,0.f,0.f,0.f,0.f,0.f,0.f,0.f,0.f,0.f,0.f,0.f};
        {   // two independent 4-deep MFMA chains (K 0-63 / 64-127)
            half8 p0 = *(const half8*)&bs[l * 8];
            half8 p4 = *(const half8*)&bs[l * 8 + 4 * 512];
            acA = __builtin_amdgcn_mfma_f32_32x32x16_f16(p0, vh[0], acA, 0, 0, 0);
            acB = __builtin_amdgcn_mfma_f32_32x32x16_f16(p4, vh[4], acB, 0, 0, 0);
            half8 p1 = *(const half8*)&bs[l * 8 + 1 * 512];
            half8 p5 = *(const half8*)&bs[l * 8 + 5 * 512];
            acA = __builtin_amdgcn_mfma_f32_32x32x16_f16(p1, vh[1], acA, 0, 0, 0);
            acB = __builtin_amdgcn_mfma_f32_32x32x16_f16(p5, vh[5], acB, 0, 0, 0);
            half8 p2 = *(const half8*)&bs[l * 8 + 2 * 512];
            half8 p6 = *(const half8*)&bs[l * 8 + 6 * 512];
            acA = __builtin_amdgcn_mfma_f32_32x32x16_f16(p2, vh[2], acA, 0, 0, 0);
            acB = __builtin_amdgcn_mfma_f32_32x32x16_f16(p6, vh[6], acB, 0, 0, 0);
            half8 p3 = *(const half8*)&bs[l * 8 + 3 * 512];
            half8 p7 = *(const half8*)&bs[l * 8 + 7 * 512];
            acA = __builtin_amdgcn_mfma_f32_32x32x16_f16(p3, vh[3], acA, 0, 0, 0);
            acB = __builtin_amdgcn_mfma_f32_32x32x16_f16(p7, vh[7], acB, 0, 0, 0);
        }
        // own ds_reads retired -> safe to restage this wave's stripe
        asm volatile("s_waitcnt lgkmcnt(0)" ::: "memory");
        if (ch + 2 < CHUNKS) STAGE(ch + 2, ch & 1);   // DMA hides under epi

        f32x16 acc = acA + acB;
        const int cb = (ch << 4) + (w << 2) + hi;     // concept 16ch+4g+hi
        // concept cb   : protos 0-7 = regs {0..3, 8..11}
        SOFT8(acc[0], acc[1], acc[2],  acc[3],  acc[8],  acc[9],  acc[10], acc[11], cb);
        // concept cb+2 : protos 0-7 = regs {4..7, 12..15}
        SOFT8(acc[4], acc[5], acc[6],  acc[7],  acc[12], acc[13], acc[14], acc[15], cb + 2);
    }

    // ---- fold dn per row: lanes l / l+32 share a row; 4 waves add ----
    {
        float t = dn;
        t += __shfl_xor(t, 32);
        if (hi == 0)
            atomicAdd(&sh_denom[a], t);
    }
    __syncthreads();

    // ---- block loss over its <=32 compacted rows (all label==1) ----
    // lp = log(denom) - LT*(sim_pos + margin) = log(denom) - ln2*simY - 1.0
    if (w == 0) {
        float s = 0.f, cc = 0.f;
        if (l < 32 && rowbase + l < np) {
            s  = logf(sh_denom[l] + 1e-8f) - LN2 * sh_simpos[l] - 1.0f;
            cc = 1.0f;
        }
#pragma unroll
        for (int off = 32; off >= 1; off >>= 1) {
            s  += __shfl_down(s, off);
            cc += __shfl_down(cc, off);
        }
        if (l == 0) {                  // plain stores; finisher reduces
            part[2 * blockIdx.x]     = s;
            part[2 * blockIdx.x + 1] = cc;
        }
    }
}

// 1 block x 512 threads: reduce the active blocks' (s, cc) partials.
__global__ __launch_bounds__(512)
void mpcl_finish(const float* __restrict__ part, const int* __restrict__ npos,
                 float* __restrict__ out)
{
    __shared__ float sh[16];
    const int tid  = threadIdx.x;
    const int lane = tid & 63;
    const int w    = tid >> 6;
    const int nact = (*npos + 31) >> 5;           // active main blocks

    float s = 0.f, cc = 0.f;
    for (int i = tid; i < nact; i += 512) {
        s  += part[2 * i];
        cc += part[2 * i + 1];
    }
#pragma unroll
    for (int off = 32; off >= 1; off >>= 1) {
        s  += __shfl_down(s, off);
        cc += __shfl_down(cc, off);
    }
    if (lane == 0) { sh[w] = s; sh[8 + w] = cc; }
    __syncthreads();
    if (tid == 0) {
        float ts = 0.f, tc = 0.f;
#pragma unroll
        for (int i = 0; i < 8; ++i) { ts += sh[i]; tc += sh[8 + i]; }
        out[0] = (tc > 0.0f) ? (ts / tc) : ts;
    }
}

extern "C" void kernel_launch(void* const* d_in, const int* in_sizes, int n_in,
                              void* d_out, int out_size, void* d_ws, size_t ws_size,
                              hipStream_t stream)
{
    const float* V      = (const float*)d_in[0];
    const int*   labels = (const int*)d_in[1];
    const float* P      = (const float*)d_in[2];
    float* out = (float*)d_out;

    int*      npos = (int*)d_ws;                        // [0]
    float*    part = (float*)((char*)d_ws + 256);       // 1024 x 2 floats
    int*      ridx = (int*)((char*)d_ws + 16384);       // 128 KB
    _Float16* Pw   = (_Float16*)((char*)d_ws + 147456); // 512 KB packed P

    mpcl_prep_compact<<<33, 1024, 0, stream>>>(P, labels, Pw, ridx, npos);
    mpcl_main<<<NBLK, 256, 0, stream>>>(V, Pw, ridx, npos, part);
    mpcl_finish<<<1, 512, 0, stream>>>(part, npos, out);
}